// Round 7
// baseline (1095.126 us; speedup 1.0000x reference)
//
#include <hip/hip_runtime.h>

#define NN 100000
#define NE 1600000
#define DI 128
#define DH 128
#define DO 64
#define BNODES 256
#define NBK ((NN + BNODES - 1) / BNODES)  // 391 buckets
#define PAD 16                             // one counter per 64B line
#define NCH 7                              // src chunks (src >> 14, 16384 rows = 4MB bf16x128 slice)
#define CSH 14
#define NPW 13                             // nodes per wave in aggregation
#define NWAVES ((NN + NPW - 1) / NPW)      // 7693

typedef unsigned int uint;
typedef unsigned short ushort;
typedef unsigned char uchar;
typedef __bf16 bf16x8 __attribute__((ext_vector_type(8)));
typedef float f32x4 __attribute__((ext_vector_type(4)));

// ---- bf16 helpers (manual, RTNE) ----
__device__ __forceinline__ float bf_lo(uint u) { return __uint_as_float(u << 16); }
__device__ __forceinline__ float bf_hi(uint u) { return __uint_as_float(u & 0xffff0000u); }
__device__ __forceinline__ ushort f2bf(float f) {
    uint u = __float_as_uint(f);
    uint r = u + 0x7fffu + ((u >> 16) & 1u);
    return (ushort)(r >> 16);
}

__global__ void k_zero(int* p, int n) {
    int i = blockIdx.x * blockDim.x + threadIdx.x;
    if (i < n) p[i] = 0;
}

// ---- Pass A: bucket histogram via LDS privatization ----
__global__ void k_bhist(const int* __restrict__ dst, int* __restrict__ bcnt) {
    __shared__ int h[NBK + 1];
    for (int i = threadIdx.x; i < NBK; i += 256) h[i] = 0;
    __syncthreads();
    for (int e = blockIdx.x * 256 + threadIdx.x; e < NE; e += gridDim.x * 256)
        atomicAdd(&h[dst[e] >> 8], 1);
    __syncthreads();
    for (int i = threadIdx.x; i < NBK; i += 256)
        if (h[i]) atomicAdd(&bcnt[i * PAD], h[i]);
}

// ---- Pass B: scan bucket counts -> bbase[0..NBK], bcur (padded) ----
__global__ void k_bscan(const int* __restrict__ bcnt, int* __restrict__ bbase,
                        int* __restrict__ bcur) {
    __shared__ int s[512];
    int t = threadIdx.x;
    int v = (t < NBK) ? bcnt[t * PAD] : 0;
    s[t] = v;
    __syncthreads();
    for (int d = 1; d < 512; d <<= 1) {
        int a = (t >= d) ? s[t - d] : 0;
        __syncthreads();
        s[t] += a;
        __syncthreads();
    }
    if (t < NBK) {
        int b = s[t] - v;  // exclusive
        bbase[t] = b;
        bcur[t * PAD] = b;
    }
    if (t == NBK - 1) bbase[NBK] = s[t];  // == NE
}

// ---- Pass C: scatter packed (src,dst) into bucket regions ----
__global__ void k_bscatter(const int* __restrict__ src, const int* __restrict__ dst,
                           int* __restrict__ bcur, uint2* __restrict__ ebuf) {
    int e = blockIdx.x * 256 + threadIdx.x;
    if (e < NE) {
        int d = dst[e];
        int p = atomicAdd(&bcur[(d >> 8) * PAD], 1);
        ebuf[p] = make_uint2((uint)src[e], (uint)d);
    }
}

// ---- Pass D: per-bucket (node,chunk) hist + scan + fill ----
// emits off[node], inv[node], cnt8[node][8] (per-chunk counts), csr grouped by (node, src-chunk)
__global__ __launch_bounds__(256) void k_bfill(const uint2* __restrict__ ebuf,
                                               const int* __restrict__ bbase,
                                               int* __restrict__ off,
                                               float* __restrict__ inv,
                                               uchar* __restrict__ cnt8,
                                               int* __restrict__ csr_src) {
    __shared__ int cnt[256 * 8];
    __shared__ int cur[256 * 8];
    __shared__ int s[256];
    int b = blockIdx.x, t = threadIdx.x;
    int ebeg = bbase[b], eend = bbase[b + 1];
#pragma unroll
    for (int k = 0; k < 8; ++k) cnt[t * 8 + k] = 0;
    __syncthreads();
    for (int e = ebeg + t; e < eend; e += 256) {
        uint2 ed = ebuf[e];
        atomicAdd(&cnt[((ed.y & 255) << 3) | (ed.x >> CSH)], 1);
    }
    __syncthreads();
    int deg = 0;
#pragma unroll
    for (int k = 0; k < 8; ++k) deg += cnt[t * 8 + k];
    s[t] = deg;
    __syncthreads();
    for (int d = 1; d < 256; d <<= 1) {
        int a = (t >= d) ? s[t - d] : 0;
        __syncthreads();
        s[t] += a;
        __syncthreads();
    }
    int base = ebeg + s[t] - deg;  // exclusive within bucket
    int node = b * 256 + t;
    uint pk0 = 0, pk1 = 0;
    int run = base;
#pragma unroll
    for (int k = 0; k < 8; ++k) {
        int c = cnt[t * 8 + k];
        cur[t * 8 + k] = run;
        run += c;
        if (k < 4) pk0 |= (uint)c << (8 * k);
        else       pk1 |= (uint)c << (8 * (k - 4));
    }
    if (node < NN) {
        off[node] = base;
        inv[node] = rsqrtf((float)deg + 1.0f);
        *(uint2*)(cnt8 + (size_t)node * 8) = make_uint2(pk0, pk1);
    }
    __syncthreads();
    for (int e = ebeg + t; e < eend; e += 256) {
        uint2 ed = ebuf[e];
        int p = atomicAdd(&cur[((ed.y & 255) << 3) | (ed.x >> CSH)], 1);
        csr_src[p] = (int)ed.x;
    }
}

// ---------------- W transpose to bf16: Wt[c][k] = bf16(W[k][c]) ----------------
__global__ void k_wt(const float* __restrict__ W, ushort* __restrict__ Wt, int K, int N) {
    int t = blockIdx.x * blockDim.x + threadIdx.x;
    if (t < K * N) {
        int c = t / K, k = t % K;
        Wt[t] = f2bf(W[k * N + c]);
    }
}

// ---------------- MFMA GEMM: one wave = 32 rows x N cols, K=128 ----------------
// epilogue scales row r by inv[r]:  out[r] = bf16(inv[r] * (A@W)[r])
template <int N, bool ABF16>
__global__ __launch_bounds__(256) void k_gemm_mfma(const void* __restrict__ Ap,
                                                   const ushort* __restrict__ Wt,
                                                   const float* __restrict__ inv,
                                                   ushort* __restrict__ out) {
    int wid = threadIdx.x >> 6;
    int lane = threadIdx.x & 63;
    int r0 = (blockIdx.x * 4 + wid) * 32;
    if (r0 >= NN) return;
    int rlo = lane & 15, khi = lane >> 4;  // khi in 0..3

    constexpr int CT = N / 16;  // 8 (N=128) or 4 (N=64)
    f32x4 acc[2][CT] = {};

#pragma unroll
    for (int ks = 0; ks < 4; ++ks) {
        bf16x8 bf[CT];
#pragma unroll
        for (int ct = 0; ct < CT; ++ct)
            bf[ct] = *(const bf16x8*)(Wt + (ct * 16 + rlo) * 128 + ks * 32 + khi * 8);
#pragma unroll
        for (int rt = 0; rt < 2; ++rt) {
            int row = r0 + rt * 16 + rlo;
            bf16x8 af;
            if (ABF16) {
                af = *(const bf16x8*)((const ushort*)Ap + (size_t)row * 128 + ks * 32 + khi * 8);
            } else {
                const float* pa = (const float*)Ap + (size_t)row * 128 + ks * 32 + khi * 8;
                float4 f0 = *(const float4*)pa;
                float4 f1 = *(const float4*)(pa + 4);
                af[0] = (__bf16)f0.x; af[1] = (__bf16)f0.y;
                af[2] = (__bf16)f0.z; af[3] = (__bf16)f0.w;
                af[4] = (__bf16)f1.x; af[5] = (__bf16)f1.y;
                af[6] = (__bf16)f1.z; af[7] = (__bf16)f1.w;
            }
#pragma unroll
            for (int ct = 0; ct < CT; ++ct)
                acc[rt][ct] = __builtin_amdgcn_mfma_f32_16x16x32_bf16(af, bf[ct], acc[rt][ct], 0, 0, 0);
        }
    }
#pragma unroll
    for (int rt = 0; rt < 2; ++rt) {
        int rowb = r0 + rt * 16 + 4 * khi;
#pragma unroll
        for (int b = 0; b < 4; ++b) {
            float sc = inv[rowb + b];
#pragma unroll
            for (int ct = 0; ct < CT; ++ct)
                out[(size_t)(rowb + b) * N + ct * 16 + rlo] = f2bf(acc[rt][ct][b] * sc);
        }
    }
}

// ---------------- chunk-major aggregation, D=128 ----------------
// tab[s] = bf16(inv[s]*h[s]); out[d] = bf16(relu(inv[d]*(sum_nbr tab[src] + tab[d]) + bias))
__global__ __launch_bounds__(256) void k_aggc128(const int* __restrict__ off,
                                                 const uchar* __restrict__ cnt8,
                                                 const int* __restrict__ csr,
                                                 const ushort* __restrict__ tab,
                                                 const float* __restrict__ inv,
                                                 const float* __restrict__ bias,
                                                 ushort* __restrict__ outb) {
    int w = blockIdx.x * 4 + (threadIdx.x >> 6);
    int lane = threadIdx.x & 63;
    int n0 = w * NPW;
    if (n0 >= NN) return;
    int nc = min(NPW, NN - n0);
    const uint* t32 = (const uint*)tab;
    float a0[NPW], a1[NPW];
    int cur[NPW];
#pragma unroll
    for (int j = 0; j < NPW; ++j) {
        a0[j] = 0.f; a1[j] = 0.f;
        cur[j] = (j < nc) ? off[n0 + j] : 0;
    }
#pragma unroll
    for (int ck = 0; ck < NCH; ++ck) {
#pragma unroll
        for (int j = 0; j < NPW; ++j) {
            if (j < nc) {
                int n = cnt8[(size_t)(n0 + j) * 8 + ck];
                int e = cur[j];
                cur[j] = e + n;
                float s0 = a0[j], s1 = a1[j];
                int i = 0;
                for (; i + 1 < n; i += 2) {
                    int sa = csr[e + i], sb = csr[e + i + 1];
                    uint ua = t32[(size_t)sa * 64 + lane];
                    uint ub = t32[(size_t)sb * 64 + lane];
                    s0 += bf_lo(ua); s1 += bf_hi(ua);
                    s0 += bf_lo(ub); s1 += bf_hi(ub);
                }
                if (i < n) {
                    int sa = csr[e + i];
                    uint ua = t32[(size_t)sa * 64 + lane];
                    s0 += bf_lo(ua); s1 += bf_hi(ua);
                }
                a0[j] = s0; a1[j] = s1;
            }
        }
    }
    float2 bb = *(const float2*)(bias + lane * 2);
#pragma unroll
    for (int j = 0; j < NPW; ++j) {
        if (j < nc) {
            int node = n0 + j;
            float invd = inv[node];
            uint us = t32[(size_t)node * 64 + lane];
            float r0 = fmaf(invd, a0[j] + bf_lo(us), bb.x);
            float r1 = fmaf(invd, a1[j] + bf_hi(us), bb.y);
            r0 = fmaxf(r0, 0.f); r1 = fmaxf(r1, 0.f);
            *(uint*)(outb + (size_t)node * 128 + lane * 2) =
                (uint)f2bf(r0) | ((uint)f2bf(r1) << 16);
        }
    }
}

// ---------------- chunk-major aggregation, D=64 -> fp32 out ----------------
__global__ __launch_bounds__(256) void k_aggc64(const int* __restrict__ off,
                                                const uchar* __restrict__ cnt8,
                                                const int* __restrict__ csr,
                                                const ushort* __restrict__ tab,
                                                const float* __restrict__ inv,
                                                const float* __restrict__ bias,
                                                float* __restrict__ out) {
    int w = blockIdx.x * 4 + (threadIdx.x >> 6);
    int lane = threadIdx.x & 63;
    int n0 = w * NPW;
    if (n0 >= NN) return;
    int nc = min(NPW, NN - n0);
    float a0[NPW];
    int cur[NPW];
#pragma unroll
    for (int j = 0; j < NPW; ++j) {
        a0[j] = 0.f;
        cur[j] = (j < nc) ? off[n0 + j] : 0;
    }
#pragma unroll
    for (int ck = 0; ck < NCH; ++ck) {
#pragma unroll
        for (int j = 0; j < NPW; ++j) {
            if (j < nc) {
                int n = cnt8[(size_t)(n0 + j) * 8 + ck];
                int e = cur[j];
                cur[j] = e + n;
                float s0 = a0[j];
                int i = 0;
                for (; i + 1 < n; i += 2) {
                    int sa = csr[e + i], sb = csr[e + i + 1];
                    float ha = __uint_as_float((uint)tab[(size_t)sa * 64 + lane] << 16);
                    float hb = __uint_as_float((uint)tab[(size_t)sb * 64 + lane] << 16);
                    s0 += ha; s0 += hb;
                }
                if (i < n) {
                    int sa = csr[e + i];
                    s0 += __uint_as_float((uint)tab[(size_t)sa * 64 + lane] << 16);
                }
                a0[j] = s0;
            }
        }
    }
    float bb = bias[lane];
#pragma unroll
    for (int j = 0; j < NPW; ++j) {
        if (j < nc) {
            int node = n0 + j;
            float invd = inv[node];
            float hs = __uint_as_float((uint)tab[(size_t)node * 64 + lane] << 16);
            out[(size_t)node * 64 + lane] = fmaf(invd, a0[j] + hs, bb);
        }
    }
}

extern "C" void kernel_launch(void* const* d_in, const int* in_sizes, int n_in,
                              void* d_out, int out_size, void* d_ws, size_t ws_size,
                              hipStream_t stream) {
    const float* x  = (const float*)d_in[0];
    const int* ei   = (const int*)d_in[1];
    const int* src  = ei;        // edge_index[0]
    const int* dst  = ei + NE;   // edge_index[1]
    const float* W1 = (const float*)d_in[2];
    const float* b1 = (const float*)d_in[3];
    const float* W2 = (const float*)d_in[4];
    const float* b2 = (const float*)d_in[5];
    float* out = (float*)d_out;

    // workspace layout (16B alignment maintained)
    int*    off     = (int*)d_ws;                        // 100004 ints
    float*  inv     = (float*)(off + 100004);            // 100004 floats
    int*    bcnt    = (int*)(inv + 100004);              // 392*16 ints (padded)
    int*    bbase   = bcnt + 392 * PAD;                  // 392+8 ints
    int*    bcur    = bbase + 400;                       // 392*16 ints (padded)
    uchar*  cnt8    = (uchar*)(bcur + 392 * PAD);        // NN*8 bytes
    int*    csr_src = (int*)(cnt8 + (size_t)NN * 8);     // 1600000 ints
    ushort* w1t     = (ushort*)(csr_src + 1600000);      // 128*128 bf16
    ushort* w2t     = w1t + 128 * 128;                   // 64*128 bf16
    ushort* h       = w2t + 64 * 128;                    // NN*128 bf16 (inv-scaled)
    ushort* hagg    = h + (size_t)NN * DH;               // NN*128 bf16
    ushort* h2      = hagg + (size_t)NN * DH;            // NN*64 bf16 (inv-scaled)
    uint2*  ebuf    = (uint2*)h2;                        // NE uint2, aliases h2 (dead until gemm2)

    // CSR build: bucket sort (A-D), emits off/inv/cnt8/csr_src (chunk-grouped)
    k_zero<<<25, 256, 0, stream>>>(bcnt, 392 * PAD);
    k_bhist<<<1024, 256, 0, stream>>>(dst, bcnt);
    k_bscan<<<1, 512, 0, stream>>>(bcnt, bbase, bcur);
    k_bscatter<<<(NE + 255) / 256, 256, 0, stream>>>(src, dst, bcur, ebuf);
    k_bfill<<<NBK, 256, 0, stream>>>(ebuf, bbase, off, inv, cnt8, csr_src);

    // weight prep
    k_wt<<<64, 256, 0, stream>>>(W1, w1t, 128, 128);
    k_wt<<<32, 256, 0, stream>>>(W2, w2t, 128, 64);

    int aggBlocks = (NWAVES + 3) / 4;  // 1924

    // layer 1: h = bf16(inv .* (x @ W1)) ; hagg = bf16(relu(inv.*(sum tab + self) + b1))
    k_gemm_mfma<DH, false><<<(NN + 127) / 128, 256, 0, stream>>>(x, w1t, inv, h);
    k_aggc128<<<aggBlocks, 256, 0, stream>>>(off, cnt8, csr_src, h, inv, b1, hagg);

    // layer 2: h2 = bf16(inv .* (hagg @ W2)) ; out = inv.*(sum tab2 + self) + b2 (fp32)
    k_gemm_mfma<DO, true><<<(NN + 127) / 128, 256, 0, stream>>>(hagg, w2t, inv, h2);
    k_aggc64<<<aggBlocks, 256, 0, stream>>>(off, cnt8, csr_src, h2, inv, b2, out);
}

// Round 8
// 341.291 us; speedup vs baseline: 3.2088x; 3.2088x over previous
//
#include <hip/hip_runtime.h>

#define NN 100000
#define NE 1600000
#define DI 128
#define DH 128
#define DO 64
#define BNODES 256
#define NBK ((NN + BNODES - 1) / BNODES)  // 391 buckets
#define PAD 16                             // one counter per 64B line

typedef unsigned int uint;
typedef unsigned short ushort;
typedef __bf16 bf16x8 __attribute__((ext_vector_type(8)));
typedef float f32x4 __attribute__((ext_vector_type(4)));

// ---- bf16 helpers (manual, RTNE) ----
__device__ __forceinline__ float bf_lo(uint u) { return __uint_as_float(u << 16); }
__device__ __forceinline__ float bf_hi(uint u) { return __uint_as_float(u & 0xffff0000u); }
__device__ __forceinline__ ushort f2bf(float f) {
    uint u = __float_as_uint(f);
    uint r = u + 0x7fffu + ((u >> 16) & 1u);
    return (ushort)(r >> 16);
}

__global__ void k_zero(int* p, int n) {
    int i = blockIdx.x * blockDim.x + threadIdx.x;
    if (i < n) p[i] = 0;
}

// ---- Pass A: bucket histogram via LDS privatization ----
__global__ void k_bhist(const int* __restrict__ dst, int* __restrict__ bcnt) {
    __shared__ int h[NBK + 1];
    for (int i = threadIdx.x; i < NBK; i += 256) h[i] = 0;
    __syncthreads();
    for (int e = blockIdx.x * 256 + threadIdx.x; e < NE; e += gridDim.x * 256)
        atomicAdd(&h[dst[e] >> 8], 1);
    __syncthreads();
    for (int i = threadIdx.x; i < NBK; i += 256)
        if (h[i]) atomicAdd(&bcnt[i * PAD], h[i]);
}

// ---- Pass B: scan bucket counts -> bbase[0..NBK], bcur (padded) ----
__global__ void k_bscan(const int* __restrict__ bcnt, int* __restrict__ bbase,
                        int* __restrict__ bcur) {
    __shared__ int s[512];
    int t = threadIdx.x;
    int v = (t < NBK) ? bcnt[t * PAD] : 0;
    s[t] = v;
    __syncthreads();
    for (int d = 1; d < 512; d <<= 1) {
        int a = (t >= d) ? s[t - d] : 0;
        __syncthreads();
        s[t] += a;
        __syncthreads();
    }
    if (t < NBK) {
        int b = s[t] - v;  // exclusive
        bbase[t] = b;
        bcur[t * PAD] = b;
    }
    if (t == NBK - 1) bbase[NBK] = s[t];  // == NE
}

// ---- Pass C: scatter packed (src,dst) into bucket regions ----
__global__ void k_bscatter(const int* __restrict__ src, const int* __restrict__ dst,
                           int* __restrict__ bcur, uint2* __restrict__ ebuf) {
    int e = blockIdx.x * 256 + threadIdx.x;
    if (e < NE) {
        int d = dst[e];
        int p = atomicAdd(&bcur[(d >> 8) * PAD], 1);
        ebuf[p] = make_uint2((uint)src[e], (uint)d);
    }
}

// ---- Pass D: per-bucket node hist + scan + fill; emits off, inv, csr ----
__global__ __launch_bounds__(256) void k_bfill(const uint2* __restrict__ ebuf,
                                               const int* __restrict__ bbase,
                                               int* __restrict__ off,
                                               float* __restrict__ inv,
                                               int* __restrict__ csr_src) {
    __shared__ int cnt[BNODES];
    __shared__ int s[BNODES];
    __shared__ int cur[BNODES];
    int b = blockIdx.x;
    int t = threadIdx.x;
    int ebeg = bbase[b];
    int eend = bbase[b + 1];
    cnt[t] = 0;
    __syncthreads();
    for (int e = ebeg + t; e < eend; e += 256)
        atomicAdd(&cnt[ebuf[e].y & 255], 1);
    __syncthreads();
    int v = cnt[t];
    s[t] = v;
    __syncthreads();
    for (int d = 1; d < 256; d <<= 1) {
        int a = (t >= d) ? s[t - d] : 0;
        __syncthreads();
        s[t] += a;
        __syncthreads();
    }
    int excl = s[t] - v;
    int node = b * BNODES + t;
    if (node < NN) {
        off[node] = ebeg + excl;
        inv[node] = rsqrtf((float)v + 1.0f);
    }
    cur[t] = ebeg + excl;
    __syncthreads();
    for (int e = ebeg + t; e < eend; e += 256) {
        uint2 ed = ebuf[e];
        int p = atomicAdd(&cur[ed.y & 255], 1);
        csr_src[p] = (int)ed.x;
    }
    if (b == 0 && t == 0) off[NN] = NE;
}

// ---------------- W transpose to bf16: Wt[c][k] = bf16(W[k][c]) ----------------
__global__ void k_wt(const float* __restrict__ W, ushort* __restrict__ Wt, int K, int N) {
    int t = blockIdx.x * blockDim.x + threadIdx.x;
    if (t < K * N) {
        int c = t / K, k = t % K;
        Wt[t] = f2bf(W[k * N + c]);
    }
}

// ---------------- MFMA GEMM: one wave = 32 rows x N cols, K=128 ----------------
// epilogue scales row r by inv[r]:  out[r] = bf16(inv[r] * (A@W)[r])
template <int N, bool ABF16>
__global__ __launch_bounds__(256) void k_gemm_mfma(const void* __restrict__ Ap,
                                                   const ushort* __restrict__ Wt,
                                                   const float* __restrict__ inv,
                                                   ushort* __restrict__ out) {
    int wid = threadIdx.x >> 6;
    int lane = threadIdx.x & 63;
    int r0 = (blockIdx.x * 4 + wid) * 32;
    if (r0 >= NN) return;
    int rlo = lane & 15, khi = lane >> 4;  // khi in 0..3

    constexpr int CT = N / 16;  // 8 (N=128) or 4 (N=64)
    f32x4 acc[2][CT] = {};

#pragma unroll
    for (int ks = 0; ks < 4; ++ks) {
        bf16x8 bf[CT];
#pragma unroll
        for (int ct = 0; ct < CT; ++ct)
            bf[ct] = *(const bf16x8*)(Wt + (ct * 16 + rlo) * 128 + ks * 32 + khi * 8);
#pragma unroll
        for (int rt = 0; rt < 2; ++rt) {
            int row = r0 + rt * 16 + rlo;
            bf16x8 af;
            if (ABF16) {
                af = *(const bf16x8*)((const ushort*)Ap + (size_t)row * 128 + ks * 32 + khi * 8);
            } else {
                const float* pa = (const float*)Ap + (size_t)row * 128 + ks * 32 + khi * 8;
                float4 f0 = *(const float4*)pa;
                float4 f1 = *(const float4*)(pa + 4);
                af[0] = (__bf16)f0.x; af[1] = (__bf16)f0.y;
                af[2] = (__bf16)f0.z; af[3] = (__bf16)f0.w;
                af[4] = (__bf16)f1.x; af[5] = (__bf16)f1.y;
                af[6] = (__bf16)f1.z; af[7] = (__bf16)f1.w;
            }
#pragma unroll
            for (int ct = 0; ct < CT; ++ct)
                acc[rt][ct] = __builtin_amdgcn_mfma_f32_16x16x32_bf16(af, bf[ct], acc[rt][ct], 0, 0, 0);
        }
    }
#pragma unroll
    for (int rt = 0; rt < 2; ++rt) {
        int rowb = r0 + rt * 16 + 4 * khi;
#pragma unroll
        for (int b = 0; b < 4; ++b) {
            float sc = inv[rowb + b];
#pragma unroll
            for (int ct = 0; ct < CT; ++ct)
                out[(size_t)(rowb + b) * N + ct * 16 + rlo] = f2bf(acc[rt][ct][b] * sc);
        }
    }
}

// ---------------- gather aggregation, D=128 ----------------
// tab[s] = bf16(inv[s]*h[s]); out[d] = bf16(relu(inv[d]*(sum tab[src] + tab[d]) + bias))
template <bool RELU>
__global__ void k_agg128(const int* __restrict__ off, const int* __restrict__ csr,
                         const ushort* __restrict__ tab, const float* __restrict__ inv,
                         const float* __restrict__ bias, ushort* __restrict__ outb) {
    int wid = threadIdx.x >> 6, lane = threadIdx.x & 63;
    int node = blockIdx.x * (blockDim.x >> 6) + wid;
    if (node >= NN) return;
    int beg = off[node], end = off[node + 1];
    const uint* t32 = (const uint*)tab;  // [NN][64] packed bf16 pairs
    float a0 = 0.f, a1 = 0.f;
    int e = beg;
    for (; e + 3 < end; e += 4) {
        int s0 = csr[e], s1 = csr[e + 1], s2 = csr[e + 2], s3 = csr[e + 3];
        uint u0 = t32[(size_t)s0 * 64 + lane];
        uint u1 = t32[(size_t)s1 * 64 + lane];
        uint u2 = t32[(size_t)s2 * 64 + lane];
        uint u3 = t32[(size_t)s3 * 64 + lane];
        a0 += bf_lo(u0); a1 += bf_hi(u0);
        a0 += bf_lo(u1); a1 += bf_hi(u1);
        a0 += bf_lo(u2); a1 += bf_hi(u2);
        a0 += bf_lo(u3); a1 += bf_hi(u3);
    }
    for (; e < end; ++e) {
        int s = csr[e];
        uint u = t32[(size_t)s * 64 + lane];
        a0 += bf_lo(u); a1 += bf_hi(u);
    }
    float invd = inv[node];
    uint us = t32[(size_t)node * 64 + lane];
    float2 b = *(const float2*)(bias + lane * 2);
    float r0 = fmaf(invd, a0 + bf_lo(us), b.x);
    float r1 = fmaf(invd, a1 + bf_hi(us), b.y);
    if (RELU) { r0 = fmaxf(r0, 0.f); r1 = fmaxf(r1, 0.f); }
    uint packed = (uint)f2bf(r0) | ((uint)f2bf(r1) << 16);
    *(uint*)(outb + (size_t)node * 128 + lane * 2) = packed;
}

// ---------------- gather aggregation, D=64 -> fp32 out ----------------
__global__ void k_agg64(const int* __restrict__ off, const int* __restrict__ csr,
                        const ushort* __restrict__ tab, const float* __restrict__ inv,
                        const float* __restrict__ bias, float* __restrict__ out) {
    int wid = threadIdx.x >> 6, lane = threadIdx.x & 63;
    int node = blockIdx.x * (blockDim.x >> 6) + wid;
    if (node >= NN) return;
    int beg = off[node], end = off[node + 1];
    float a0 = 0.f;
    int e = beg;
    for (; e + 3 < end; e += 4) {
        int s0 = csr[e], s1 = csr[e + 1], s2 = csr[e + 2], s3 = csr[e + 3];
        float h0 = __uint_as_float((uint)tab[(size_t)s0 * 64 + lane] << 16);
        float h1 = __uint_as_float((uint)tab[(size_t)s1 * 64 + lane] << 16);
        float h2 = __uint_as_float((uint)tab[(size_t)s2 * 64 + lane] << 16);
        float h3 = __uint_as_float((uint)tab[(size_t)s3 * 64 + lane] << 16);
        a0 += h0; a0 += h1; a0 += h2; a0 += h3;
    }
    for (; e < end; ++e) {
        int s = csr[e];
        a0 += __uint_as_float((uint)tab[(size_t)s * 64 + lane] << 16);
    }
    float invd = inv[node];
    float hs = __uint_as_float((uint)tab[(size_t)node * 64 + lane] << 16);
    out[(size_t)node * 64 + lane] = fmaf(invd, a0 + hs, bias[lane]);
}

extern "C" void kernel_launch(void* const* d_in, const int* in_sizes, int n_in,
                              void* d_out, int out_size, void* d_ws, size_t ws_size,
                              hipStream_t stream) {
    const float* x  = (const float*)d_in[0];
    const int* ei   = (const int*)d_in[1];
    const int* src  = ei;        // edge_index[0]
    const int* dst  = ei + NE;   // edge_index[1]
    const float* W1 = (const float*)d_in[2];
    const float* b1 = (const float*)d_in[3];
    const float* W2 = (const float*)d_in[4];
    const float* b2 = (const float*)d_in[5];
    float* out = (float*)d_out;

    // workspace layout (16B alignment maintained)
    int*    off     = (int*)d_ws;                        // 100004 ints
    float*  inv     = (float*)(off + 100004);            // 100004 floats
    int*    bcnt    = (int*)(inv + 100004);              // 392*16 ints (padded)
    int*    bbase   = bcnt + 392 * PAD;                  // 392+8 ints
    int*    bcur    = bbase + 400;                       // 392*16 ints (padded)
    int*    csr_src = bcur + 392 * PAD;                  // 1600000 ints
    ushort* w1t     = (ushort*)(csr_src + 1600000);      // 128*128 bf16
    ushort* w2t     = w1t + 128 * 128;                   // 64*128 bf16
    ushort* h       = w2t + 64 * 128;                    // NN*128 bf16 (inv-scaled)
    ushort* hagg    = h + (size_t)NN * DH;               // NN*128 bf16
    ushort* h2      = hagg + (size_t)NN * DH;            // NN*64 bf16 (inv-scaled)
    uint2*  ebuf    = (uint2*)h2;                        // NE uint2, aliases h2 (dead until gemm2)

    // CSR build: bucket sort (A-D), emits off/inv/csr_src
    k_zero<<<25, 256, 0, stream>>>(bcnt, 392 * PAD);
    k_bhist<<<1024, 256, 0, stream>>>(dst, bcnt);
    k_bscan<<<1, 512, 0, stream>>>(bcnt, bbase, bcur);
    k_bscatter<<<(NE + 255) / 256, 256, 0, stream>>>(src, dst, bcur, ebuf);
    k_bfill<<<NBK, 256, 0, stream>>>(ebuf, bbase, off, inv, csr_src);

    // weight prep
    k_wt<<<64, 256, 0, stream>>>(W1, w1t, 128, 128);
    k_wt<<<32, 256, 0, stream>>>(W2, w2t, 128, 64);

    // layer 1: h = bf16(inv .* (x @ W1)) ; hagg = bf16(relu(inv.*(sum tab + self) + b1))
    k_gemm_mfma<DH, false><<<(NN + 127) / 128, 256, 0, stream>>>(x, w1t, inv, h);
    k_agg128<true><<<NN / 4, 256, 0, stream>>>(off, csr_src, h, inv, b1, hagg);

    // layer 2: h2 = bf16(inv .* (hagg @ W2)) ; out = inv.*(sum tab2 + self) + b2 (fp32)
    k_gemm_mfma<DO, true><<<(NN + 127) / 128, 256, 0, stream>>>(hagg, w2t, inv, h2);
    k_agg64<<<NN / 4, 256, 0, stream>>>(off, csr_src, h2, inv, b2, out);
}

// Round 9
// 251.043 us; speedup vs baseline: 4.3623x; 1.3595x over previous
//
#include <hip/hip_runtime.h>

#define NN 100000
#define NE 1600000
#define DI 128
#define DH 128
#define DO 64
#define NBK 98            // buckets of 1024 nodes (dst >> 10)
#define SLOT 18432        // per-bucket region capacity (mean 16327 + ~16 sigma)
#define PAD 16            // one counter per 64B line
#define EPB 8192          // edges per scatter block
#define NSB ((NE + EPB - 1) / EPB)  // 196

typedef unsigned int uint;
typedef unsigned short ushort;
typedef unsigned char uchar;
typedef __bf16 bf16x8 __attribute__((ext_vector_type(8)));
typedef float f32x4 __attribute__((ext_vector_type(4)));

// ---- bf16 helpers (manual, RTNE) ----
__device__ __forceinline__ float bf_lo(uint u) { return __uint_as_float(u << 16); }
__device__ __forceinline__ float bf_hi(uint u) { return __uint_as_float(u & 0xffff0000u); }
__device__ __forceinline__ ushort f2bf(float f) {
    uint u = __float_as_uint(f);
    uint r = u + 0x7fffu + ((u >> 16) & 1u);
    return (ushort)(r >> 16);
}

// ---- init fixed bucket cursors: bcur[b] = b*SLOT ----
__global__ void k_binit(int* __restrict__ bcur) {
    int t = threadIdx.x;
    if (t < NBK) bcur[t * PAD] = t * SLOT;
}

// ---- staged bucket scatter: LDS counting sort per 8192-edge block ----
// emits ebuf[p] = (src<<10) | (dst&1023), grouped into per-bucket regions
__global__ __launch_bounds__(512) void k_bscatter(const int* __restrict__ src,
                                                  const int* __restrict__ dst,
                                                  int* __restrict__ bcur,
                                                  uint* __restrict__ ebuf) {
    __shared__ uint stage[EPB];       // 32 KB
    __shared__ uchar bktid[EPB];      // 8 KB
    __shared__ int lcnt[NBK];
    __shared__ int loff[NBK];
    __shared__ int gbase[NBK];
    int t = threadIdx.x;
    int e0 = blockIdx.x * EPB;
    int n = min(EPB, NE - e0);
    for (int i = t; i < NBK; i += 512) lcnt[i] = 0;
    __syncthreads();
    for (int i = t; i < n; i += 512)
        atomicAdd(&lcnt[dst[e0 + i] >> 10], 1);
    __syncthreads();
    if (t == 0) {
        int r = 0;
        for (int i = 0; i < NBK; ++i) { loff[i] = r; r += lcnt[i]; }
    }
    __syncthreads();
    if (t < NBK) {
        gbase[t] = atomicAdd(&bcur[t * PAD], lcnt[t]);
        lcnt[t] = loff[t];  // becomes local cursor
    }
    __syncthreads();
    for (int i = t; i < n; i += 512) {
        int d = dst[e0 + i];
        int s = src[e0 + i];
        int b = d >> 10;
        int p = atomicAdd(&lcnt[b], 1);
        stage[p] = ((uint)s << 10) | (uint)(d & 1023);
        bktid[p] = (uchar)b;
    }
    __syncthreads();
    for (int j = t; j < n; j += 512) {
        int b = bktid[j];
        ebuf[gbase[b] + (j - loff[b])] = stage[j];
    }
}

// ---- per-bucket (1024 nodes) hist + scan + fill; emits offdeg, inv, csr ----
__global__ __launch_bounds__(1024) void k_bfill(const uint* __restrict__ ebuf,
                                                const int* __restrict__ bcur,
                                                uint2* __restrict__ offdeg,
                                                float* __restrict__ inv,
                                                int* __restrict__ csr_src) {
    __shared__ int cnt[1024];
    __shared__ int s[1024];
    __shared__ int cur[1024];
    int b = blockIdx.x, t = threadIdx.x;
    int ebeg = b * SLOT;
    int eend = bcur[b * PAD];
    cnt[t] = 0;
    __syncthreads();
    for (int e = ebeg + t; e < eend; e += 1024)
        atomicAdd(&cnt[ebuf[e] & 1023], 1);
    __syncthreads();
    int v = cnt[t];
    s[t] = v;
    __syncthreads();
    for (int d = 1; d < 1024; d <<= 1) {
        int a = (t >= d) ? s[t - d] : 0;
        __syncthreads();
        s[t] += a;
        __syncthreads();
    }
    int beg = ebeg + s[t] - v;  // exclusive within bucket
    int node = b * 1024 + t;
    if (node < NN) {
        offdeg[node] = make_uint2((uint)beg, (uint)v);
        inv[node] = rsqrtf((float)v + 1.0f);
    }
    cur[t] = beg;
    __syncthreads();
    for (int e = ebeg + t; e < eend; e += 1024) {
        uint ed = ebuf[e];
        int p = atomicAdd(&cur[ed & 1023], 1);
        csr_src[p] = (int)(ed >> 10);
    }
}

// ---------------- W transpose to bf16: Wt[c][k] = bf16(W[k][c]) ----------------
__global__ void k_wt(const float* __restrict__ W, ushort* __restrict__ Wt, int K, int N) {
    int t = blockIdx.x * blockDim.x + threadIdx.x;
    if (t < K * N) {
        int c = t / K, k = t % K;
        Wt[t] = f2bf(W[k * N + c]);
    }
}

// ---------------- MFMA GEMM: one wave = 32 rows x N cols, K=128 ----------------
// epilogue scales row r by inv[r]:  out[r] = bf16(inv[r] * (A@W)[r])
template <int N, bool ABF16>
__global__ __launch_bounds__(256) void k_gemm_mfma(const void* __restrict__ Ap,
                                                   const ushort* __restrict__ Wt,
                                                   const float* __restrict__ inv,
                                                   ushort* __restrict__ out) {
    int wid = threadIdx.x >> 6;
    int lane = threadIdx.x & 63;
    int r0 = (blockIdx.x * 4 + wid) * 32;
    if (r0 >= NN) return;
    int rlo = lane & 15, khi = lane >> 4;  // khi in 0..3

    constexpr int CT = N / 16;  // 8 (N=128) or 4 (N=64)
    f32x4 acc[2][CT] = {};

#pragma unroll
    for (int ks = 0; ks < 4; ++ks) {
        bf16x8 bf[CT];
#pragma unroll
        for (int ct = 0; ct < CT; ++ct)
            bf[ct] = *(const bf16x8*)(Wt + (ct * 16 + rlo) * 128 + ks * 32 + khi * 8);
#pragma unroll
        for (int rt = 0; rt < 2; ++rt) {
            int row = r0 + rt * 16 + rlo;
            bf16x8 af;
            if (ABF16) {
                af = *(const bf16x8*)((const ushort*)Ap + (size_t)row * 128 + ks * 32 + khi * 8);
            } else {
                const float* pa = (const float*)Ap + (size_t)row * 128 + ks * 32 + khi * 8;
                float4 f0 = *(const float4*)pa;
                float4 f1 = *(const float4*)(pa + 4);
                af[0] = (__bf16)f0.x; af[1] = (__bf16)f0.y;
                af[2] = (__bf16)f0.z; af[3] = (__bf16)f0.w;
                af[4] = (__bf16)f1.x; af[5] = (__bf16)f1.y;
                af[6] = (__bf16)f1.z; af[7] = (__bf16)f1.w;
            }
#pragma unroll
            for (int ct = 0; ct < CT; ++ct)
                acc[rt][ct] = __builtin_amdgcn_mfma_f32_16x16x32_bf16(af, bf[ct], acc[rt][ct], 0, 0, 0);
        }
    }
#pragma unroll
    for (int rt = 0; rt < 2; ++rt) {
        int rowb = r0 + rt * 16 + 4 * khi;
#pragma unroll
        for (int b = 0; b < 4; ++b) {
            float sc = inv[rowb + b];
#pragma unroll
            for (int ct = 0; ct < CT; ++ct)
                out[(size_t)(rowb + b) * N + ct * 16 + rlo] = f2bf(acc[rt][ct][b] * sc);
        }
    }
}

// ---------------- gather aggregation, D=128 ----------------
// tab[s] = bf16(inv[s]*h[s]); out[d] = bf16(relu(inv[d]*(sum tab[src] + tab[d]) + bias))
template <bool RELU>
__global__ void k_agg128(const uint2* __restrict__ offdeg, const int* __restrict__ csr,
                         const ushort* __restrict__ tab, const float* __restrict__ inv,
                         const float* __restrict__ bias, ushort* __restrict__ outb) {
    int wid = threadIdx.x >> 6, lane = threadIdx.x & 63;
    int node = blockIdx.x * (blockDim.x >> 6) + wid;
    if (node >= NN) return;
    uint2 od = offdeg[node];
    int beg = (int)od.x, end = beg + (int)od.y;
    const uint* t32 = (const uint*)tab;  // [NN][64] packed bf16 pairs
    float a0 = 0.f, a1 = 0.f;
    int e = beg;
    for (; e + 3 < end; e += 4) {
        int s0 = csr[e], s1 = csr[e + 1], s2 = csr[e + 2], s3 = csr[e + 3];
        uint u0 = t32[(size_t)s0 * 64 + lane];
        uint u1 = t32[(size_t)s1 * 64 + lane];
        uint u2 = t32[(size_t)s2 * 64 + lane];
        uint u3 = t32[(size_t)s3 * 64 + lane];
        a0 += bf_lo(u0); a1 += bf_hi(u0);
        a0 += bf_lo(u1); a1 += bf_hi(u1);
        a0 += bf_lo(u2); a1 += bf_hi(u2);
        a0 += bf_lo(u3); a1 += bf_hi(u3);
    }
    for (; e < end; ++e) {
        int s = csr[e];
        uint u = t32[(size_t)s * 64 + lane];
        a0 += bf_lo(u); a1 += bf_hi(u);
    }
    float invd = inv[node];
    uint us = t32[(size_t)node * 64 + lane];
    float2 b = *(const float2*)(bias + lane * 2);
    float r0 = fmaf(invd, a0 + bf_lo(us), b.x);
    float r1 = fmaf(invd, a1 + bf_hi(us), b.y);
    if (RELU) { r0 = fmaxf(r0, 0.f); r1 = fmaxf(r1, 0.f); }
    uint packed = (uint)f2bf(r0) | ((uint)f2bf(r1) << 16);
    *(uint*)(outb + (size_t)node * 128 + lane * 2) = packed;
}

// ---------------- gather aggregation, D=64 -> fp32 out ----------------
__global__ void k_agg64(const uint2* __restrict__ offdeg, const int* __restrict__ csr,
                        const ushort* __restrict__ tab, const float* __restrict__ inv,
                        const float* __restrict__ bias, float* __restrict__ out) {
    int wid = threadIdx.x >> 6, lane = threadIdx.x & 63;
    int node = blockIdx.x * (blockDim.x >> 6) + wid;
    if (node >= NN) return;
    uint2 od = offdeg[node];
    int beg = (int)od.x, end = beg + (int)od.y;
    float a0 = 0.f;
    int e = beg;
    for (; e + 3 < end; e += 4) {
        int s0 = csr[e], s1 = csr[e + 1], s2 = csr[e + 2], s3 = csr[e + 3];
        float h0 = __uint_as_float((uint)tab[(size_t)s0 * 64 + lane] << 16);
        float h1 = __uint_as_float((uint)tab[(size_t)s1 * 64 + lane] << 16);
        float h2 = __uint_as_float((uint)tab[(size_t)s2 * 64 + lane] << 16);
        float h3 = __uint_as_float((uint)tab[(size_t)s3 * 64 + lane] << 16);
        a0 += h0; a0 += h1; a0 += h2; a0 += h3;
    }
    for (; e < end; ++e) {
        int s = csr[e];
        a0 += __uint_as_float((uint)tab[(size_t)s * 64 + lane] << 16);
    }
    float invd = inv[node];
    float hs = __uint_as_float((uint)tab[(size_t)node * 64 + lane] << 16);
    out[(size_t)node * 64 + lane] = fmaf(invd, a0 + hs, bias[lane]);
}

extern "C" void kernel_launch(void* const* d_in, const int* in_sizes, int n_in,
                              void* d_out, int out_size, void* d_ws, size_t ws_size,
                              hipStream_t stream) {
    const float* x  = (const float*)d_in[0];
    const int* ei   = (const int*)d_in[1];
    const int* src  = ei;        // edge_index[0]
    const int* dst  = ei + NE;   // edge_index[1]
    const float* W1 = (const float*)d_in[2];
    const float* b1 = (const float*)d_in[3];
    const float* W2 = (const float*)d_in[4];
    const float* b2 = (const float*)d_in[5];
    float* out = (float*)d_out;

    // workspace layout (16B alignment maintained)
    uint2*  offdeg  = (uint2*)d_ws;                      // NN uint2
    float*  inv     = (float*)(offdeg + NN);             // 100004 floats
    int*    bcur    = (int*)(inv + 100004);              // 98*16 ints (padded)
    int*    csr_src = bcur + NBK * PAD;                  // 98*18432 ints (slotted)
    ushort* w1t     = (ushort*)(csr_src + NBK * SLOT);   // 128*128 bf16
    ushort* w2t     = w1t + 128 * 128;                   // 64*128 bf16
    ushort* h       = w2t + 64 * 128;                    // NN*128 bf16 (inv-scaled)
    ushort* hagg    = h + (size_t)NN * DH;               // NN*128 bf16
    ushort* h2      = hagg + (size_t)NN * DH;            // NN*64 bf16 (inv-scaled)
    uint*   ebuf    = (uint*)h2;                         // 98*18432 uint, aliases h2 (dead until gemm2)

    // CSR build: staged bucket scatter + per-bucket fill
    k_binit<<<1, 128, 0, stream>>>(bcur);
    k_bscatter<<<NSB, 512, 0, stream>>>(src, dst, bcur, ebuf);
    k_bfill<<<NBK, 1024, 0, stream>>>(ebuf, bcur, offdeg, inv, csr_src);

    // weight prep
    k_wt<<<64, 256, 0, stream>>>(W1, w1t, 128, 128);
    k_wt<<<32, 256, 0, stream>>>(W2, w2t, 128, 64);

    // layer 1: h = bf16(inv .* (x @ W1)) ; hagg = bf16(relu(inv.*(sum tab + self) + b1))
    k_gemm_mfma<DH, false><<<(NN + 127) / 128, 256, 0, stream>>>(x, w1t, inv, h);
    k_agg128<true><<<NN / 4, 256, 0, stream>>>(offdeg, csr_src, h, inv, b1, hagg);

    // layer 2: h2 = bf16(inv .* (hagg @ W2)) ; out = inv.*(sum tab2 + self) + b2 (fp32)
    k_gemm_mfma<DO, true><<<(NN + 127) / 128, 256, 0, stream>>>(hagg, w2t, inv, h2);
    k_agg64<<<NN / 4, 256, 0, stream>>>(offdeg, csr_src, h2, inv, b2, out);
}

// Round 10
// 244.278 us; speedup vs baseline: 4.4831x; 1.0277x over previous
//
#include <hip/hip_runtime.h>

#define NN 100000
#define NE 1600000
#define DI 128
#define DH 128
#define DO 64
#define NBK 391           // buckets of 256 nodes (dst >> 8)
#define SLOT 5120         // per-bucket slot capacity (mean 4092 + 16 sigma)
#define PAD 16            // one counter per 64B line
#define EPB 8192          // edges per scatter block
#define NSB ((NE + EPB - 1) / EPB)  // 196

typedef unsigned int uint;
typedef unsigned short ushort;
typedef __bf16 bf16x8 __attribute__((ext_vector_type(8)));
typedef float f32x4 __attribute__((ext_vector_type(4)));

// ---- bf16 helpers (manual, RTNE) ----
__device__ __forceinline__ float bf_lo(uint u) { return __uint_as_float(u << 16); }
__device__ __forceinline__ float bf_hi(uint u) { return __uint_as_float(u & 0xffff0000u); }
__device__ __forceinline__ ushort f2bf(float f) {
    uint u = __float_as_uint(f);
    uint r = u + 0x7fffu + ((u >> 16) & 1u);
    return (ushort)(r >> 16);
}

// ---- prep: bucket cursor init + both weight transposes (bf16) ----
__global__ void k_prep(const float* __restrict__ W1, const float* __restrict__ W2,
                       ushort* __restrict__ w1t, ushort* __restrict__ w2t,
                       int* __restrict__ bcur) {
    int t = blockIdx.x * 256 + threadIdx.x;
    if (t < NBK) bcur[t * PAD] = t * SLOT;
    if (t < 128 * 128) {
        int c = t >> 7, k = t & 127;
        w1t[t] = f2bf(W1[k * 128 + c]);
    } else if (t < 128 * 128 + 64 * 128) {
        int u = t - 128 * 128;
        int c = u >> 7, k = u & 127;
        w2t[u] = f2bf(W2[k * 64 + c]);
    }
}

// ---- staged bucket scatter: LDS counting sort per 8192-edge block ----
// emits ebuf[p] = (src<<8) | (dst&255), grouped into per-bucket slot regions
__global__ __launch_bounds__(512) void k_bscatter(const int* __restrict__ src,
                                                  const int* __restrict__ dst,
                                                  int* __restrict__ bcur,
                                                  uint* __restrict__ ebuf) {
    __shared__ uint stage[EPB];        // 32 KB
    __shared__ ushort bktid[EPB];      // 16 KB
    __shared__ int lcnt[NBK];
    __shared__ int loff[NBK];
    __shared__ int gbase[NBK];
    __shared__ int s[512];
    int t = threadIdx.x;
    int e0 = blockIdx.x * EPB;
    int n = min(EPB, NE - e0);
    for (int i = t; i < NBK; i += 512) lcnt[i] = 0;
    __syncthreads();
    for (int i = t; i < n; i += 512)
        atomicAdd(&lcnt[dst[e0 + i] >> 8], 1);
    __syncthreads();
    int myc = (t < NBK) ? lcnt[t] : 0;
    s[t] = myc;
    __syncthreads();
    for (int d = 1; d < 512; d <<= 1) {
        int a = (t >= d) ? s[t - d] : 0;
        __syncthreads();
        s[t] += a;
        __syncthreads();
    }
    if (t < NBK) {
        loff[t] = s[t] - myc;                       // exclusive local offset
        gbase[t] = atomicAdd(&bcur[t * PAD], myc);  // global region base
        lcnt[t] = s[t] - myc;                       // becomes local cursor
    }
    __syncthreads();
    for (int i = t; i < n; i += 512) {
        int d = dst[e0 + i];
        int sv = src[e0 + i];
        int b = d >> 8;
        int p = atomicAdd(&lcnt[b], 1);
        stage[p] = ((uint)sv << 8) | (uint)(d & 255);
        bktid[p] = (ushort)b;
    }
    __syncthreads();
    for (int j = t; j < n; j += 512) {
        int b = bktid[j];
        ebuf[gbase[b] + (j - loff[b])] = stage[j];
    }
}

// ---- per-bucket (256 nodes) hist + scan + fill; emits offdeg, inv, csr ----
__global__ __launch_bounds__(256) void k_bfill(const uint* __restrict__ ebuf,
                                               const int* __restrict__ bcur,
                                               uint2* __restrict__ offdeg,
                                               float* __restrict__ inv,
                                               int* __restrict__ csr_src) {
    __shared__ int cnt[256];
    __shared__ int s[256];
    __shared__ int cur[256];
    int b = blockIdx.x, t = threadIdx.x;
    int ebeg = b * SLOT;
    int eend = bcur[b * PAD];
    cnt[t] = 0;
    __syncthreads();
    for (int e = ebeg + t; e < eend; e += 256)
        atomicAdd(&cnt[ebuf[e] & 255], 1);
    __syncthreads();
    int v = cnt[t];
    s[t] = v;
    __syncthreads();
    for (int d = 1; d < 256; d <<= 1) {
        int a = (t >= d) ? s[t - d] : 0;
        __syncthreads();
        s[t] += a;
        __syncthreads();
    }
    int beg = ebeg + s[t] - v;  // exclusive within bucket
    int node = b * 256 + t;
    if (node < NN) {
        offdeg[node] = make_uint2((uint)beg, (uint)v);
        inv[node] = rsqrtf((float)v + 1.0f);
    }
    cur[t] = beg;
    __syncthreads();
    for (int e = ebeg + t; e < eend; e += 256) {
        uint ed = ebuf[e];
        int p = atomicAdd(&cur[ed & 255], 1);
        csr_src[p] = (int)(ed >> 8);
    }
}

// ---------------- MFMA GEMM: one wave = 32 rows x N cols, K=128 ----------------
// epilogue scales row r by inv[r]:  out[r] = bf16(inv[r] * (A@W)[r])
template <int N, bool ABF16>
__global__ __launch_bounds__(256) void k_gemm_mfma(const void* __restrict__ Ap,
                                                   const ushort* __restrict__ Wt,
                                                   const float* __restrict__ inv,
                                                   ushort* __restrict__ out) {
    int wid = threadIdx.x >> 6;
    int lane = threadIdx.x & 63;
    int r0 = (blockIdx.x * 4 + wid) * 32;
    if (r0 >= NN) return;
    int rlo = lane & 15, khi = lane >> 4;  // khi in 0..3

    constexpr int CT = N / 16;  // 8 (N=128) or 4 (N=64)
    f32x4 acc[2][CT] = {};

#pragma unroll
    for (int ks = 0; ks < 4; ++ks) {
        bf16x8 bf[CT];
#pragma unroll
        for (int ct = 0; ct < CT; ++ct)
            bf[ct] = *(const bf16x8*)(Wt + (ct * 16 + rlo) * 128 + ks * 32 + khi * 8);
#pragma unroll
        for (int rt = 0; rt < 2; ++rt) {
            int row = r0 + rt * 16 + rlo;
            bf16x8 af;
            if (ABF16) {
                af = *(const bf16x8*)((const ushort*)Ap + (size_t)row * 128 + ks * 32 + khi * 8);
            } else {
                const float* pa = (const float*)Ap + (size_t)row * 128 + ks * 32 + khi * 8;
                float4 f0 = *(const float4*)pa;
                float4 f1 = *(const float4*)(pa + 4);
                af[0] = (__bf16)f0.x; af[1] = (__bf16)f0.y;
                af[2] = (__bf16)f0.z; af[3] = (__bf16)f0.w;
                af[4] = (__bf16)f1.x; af[5] = (__bf16)f1.y;
                af[6] = (__bf16)f1.z; af[7] = (__bf16)f1.w;
            }
#pragma unroll
            for (int ct = 0; ct < CT; ++ct)
                acc[rt][ct] = __builtin_amdgcn_mfma_f32_16x16x32_bf16(af, bf[ct], acc[rt][ct], 0, 0, 0);
        }
    }
#pragma unroll
    for (int rt = 0; rt < 2; ++rt) {
        int rowb = r0 + rt * 16 + 4 * khi;
#pragma unroll
        for (int b = 0; b < 4; ++b) {
            float sc = inv[rowb + b];
#pragma unroll
            for (int ct = 0; ct < CT; ++ct)
                out[(size_t)(rowb + b) * N + ct * 16 + rlo] = f2bf(acc[rt][ct][b] * sc);
        }
    }
}

// ---------------- gather aggregation, D=128 ----------------
// tab[s] = bf16(inv[s]*h[s]); out[d] = bf16(relu(inv[d]*(sum tab[src] + tab[d]) + bias))
template <bool RELU>
__global__ void k_agg128(const uint2* __restrict__ offdeg, const int* __restrict__ csr,
                         const ushort* __restrict__ tab, const float* __restrict__ inv,
                         const float* __restrict__ bias, ushort* __restrict__ outb) {
    int wid = threadIdx.x >> 6, lane = threadIdx.x & 63;
    int node = blockIdx.x * (blockDim.x >> 6) + wid;
    if (node >= NN) return;
    uint2 od = offdeg[node];
    int beg = (int)od.x, end = beg + (int)od.y;
    const uint* t32 = (const uint*)tab;  // [NN][64] packed bf16 pairs
    float a0 = 0.f, a1 = 0.f;
    int e = beg;
    for (; e + 3 < end; e += 4) {
        int s0 = csr[e], s1 = csr[e + 1], s2 = csr[e + 2], s3 = csr[e + 3];
        uint u0 = t32[(size_t)s0 * 64 + lane];
        uint u1 = t32[(size_t)s1 * 64 + lane];
        uint u2 = t32[(size_t)s2 * 64 + lane];
        uint u3 = t32[(size_t)s3 * 64 + lane];
        a0 += bf_lo(u0); a1 += bf_hi(u0);
        a0 += bf_lo(u1); a1 += bf_hi(u1);
        a0 += bf_lo(u2); a1 += bf_hi(u2);
        a0 += bf_lo(u3); a1 += bf_hi(u3);
    }
    for (; e < end; ++e) {
        int s = csr[e];
        uint u = t32[(size_t)s * 64 + lane];
        a0 += bf_lo(u); a1 += bf_hi(u);
    }
    float invd = inv[node];
    uint us = t32[(size_t)node * 64 + lane];
    float2 b = *(const float2*)(bias + lane * 2);
    float r0 = fmaf(invd, a0 + bf_lo(us), b.x);
    float r1 = fmaf(invd, a1 + bf_hi(us), b.y);
    if (RELU) { r0 = fmaxf(r0, 0.f); r1 = fmaxf(r1, 0.f); }
    uint packed = (uint)f2bf(r0) | ((uint)f2bf(r1) << 16);
    *(uint*)(outb + (size_t)node * 128 + lane * 2) = packed;
}

// ---------------- gather aggregation, D=64 -> fp32 out ----------------
__global__ void k_agg64(const uint2* __restrict__ offdeg, const int* __restrict__ csr,
                        const ushort* __restrict__ tab, const float* __restrict__ inv,
                        const float* __restrict__ bias, float* __restrict__ out) {
    int wid = threadIdx.x >> 6, lane = threadIdx.x & 63;
    int node = blockIdx.x * (blockDim.x >> 6) + wid;
    if (node >= NN) return;
    uint2 od = offdeg[node];
    int beg = (int)od.x, end = beg + (int)od.y;
    float a0 = 0.f;
    int e = beg;
    for (; e + 3 < end; e += 4) {
        int s0 = csr[e], s1 = csr[e + 1], s2 = csr[e + 2], s3 = csr[e + 3];
        float h0 = __uint_as_float((uint)tab[(size_t)s0 * 64 + lane] << 16);
        float h1 = __uint_as_float((uint)tab[(size_t)s1 * 64 + lane] << 16);
        float h2 = __uint_as_float((uint)tab[(size_t)s2 * 64 + lane] << 16);
        float h3 = __uint_as_float((uint)tab[(size_t)s3 * 64 + lane] << 16);
        a0 += h0; a0 += h1; a0 += h2; a0 += h3;
    }
    for (; e < end; ++e) {
        int s = csr[e];
        a0 += __uint_as_float((uint)tab[(size_t)s * 64 + lane] << 16);
    }
    float invd = inv[node];
    float hs = __uint_as_float((uint)tab[(size_t)node * 64 + lane] << 16);
    out[(size_t)node * 64 + lane] = fmaf(invd, a0 + hs, bias[lane]);
}

extern "C" void kernel_launch(void* const* d_in, const int* in_sizes, int n_in,
                              void* d_out, int out_size, void* d_ws, size_t ws_size,
                              hipStream_t stream) {
    const float* x  = (const float*)d_in[0];
    const int* ei   = (const int*)d_in[1];
    const int* src  = ei;        // edge_index[0]
    const int* dst  = ei + NE;   // edge_index[1]
    const float* W1 = (const float*)d_in[2];
    const float* b1 = (const float*)d_in[3];
    const float* W2 = (const float*)d_in[4];
    const float* b2 = (const float*)d_in[5];
    float* out = (float*)d_out;

    // workspace layout (16B alignment maintained)
    uint2*  offdeg  = (uint2*)d_ws;                      // NN uint2
    float*  inv     = (float*)(offdeg + NN);             // 100004 floats
    int*    bcur    = (int*)(inv + 100004);              // NBK*16 ints (padded)
    int*    csr_src = bcur + NBK * PAD;                  // NBK*SLOT ints (slotted)
    ushort* w1t     = (ushort*)(csr_src + NBK * SLOT);   // 128*128 bf16
    ushort* w2t     = w1t + 128 * 128;                   // 64*128 bf16
    ushort* h       = w2t + 64 * 128;                    // NN*128 bf16 (inv-scaled)
    ushort* hagg    = h + (size_t)NN * DH;               // NN*128 bf16
    ushort* h2      = hagg + (size_t)NN * DH;            // NN*64 bf16 (inv-scaled)
    uint*   ebuf    = (uint*)h2;                         // NBK*SLOT uint, aliases h2 (dead until gemm2)

    // prep (bcur init + weight transposes), then CSR build
    k_prep<<<96, 256, 0, stream>>>(W1, W2, w1t, w2t, bcur);
    k_bscatter<<<NSB, 512, 0, stream>>>(src, dst, bcur, ebuf);
    k_bfill<<<NBK, 256, 0, stream>>>(ebuf, bcur, offdeg, inv, csr_src);

    // layer 1: h = bf16(inv .* (x @ W1)) ; hagg = bf16(relu(inv.*(sum tab + self) + b1))
    k_gemm_mfma<DH, false><<<(NN + 127) / 128, 256, 0, stream>>>(x, w1t, inv, h);
    k_agg128<true><<<NN / 4, 256, 0, stream>>>(offdeg, csr_src, h, inv, b1, hagg);

    // layer 2: h2 = bf16(inv .* (hagg @ W2)) ; out = inv.*(sum tab2 + self) + b2 (fp32)
    k_gemm_mfma<DO, true><<<(NN + 127) / 128, 256, 0, stream>>>(hagg, w2t, inv, h2);
    k_agg64<<<NN / 4, 256, 0, stream>>>(offdeg, csr_src, h2, inv, b2, out);
}